// Round 6
// baseline (118.022 us; speedup 1.0000x reference)
//
#include <hip/hip_runtime.h>
#include <hip/hip_bf16.h>

// Problem constants (Atten_tit): B=16, T=256, K=256, H=512, A=49
#define B_ 16
#define T_ 256
#define K_ 256
#define H_ 512
#define A_ 49
#define APAD 64
#define TT 8   // t-rows per kZ block

typedef __attribute__((ext_vector_type(8))) short short8;   // bf16x8
typedef __attribute__((ext_vector_type(4))) float f32x4;

__device__ __forceinline__ ushort f2bf(float f) {
    uint u = __builtin_bit_cast(uint, f);
    u += 0x7FFF + ((u >> 16) & 1);   // RNE
    return (ushort)(u >> 16);
}

// split f32 -> bf16 hi + bf16 lo (residual); hi+lo ~ 17 mantissa bits.
__device__ __forceinline__ void cvt_hilo(float4 v0, float4 v1, short8& hi, short8& lo) {
    float v[8] = {v0.x, v0.y, v0.z, v0.w, v1.x, v1.y, v1.z, v1.w};
    #pragma unroll
    for (int i = 0; i < 8; ++i) {
        ushort h = f2bf(v[i]);
        float hf = __builtin_bit_cast(float, (uint)h << 16);
        hi[i] = (short)h;
        lo[i] = (short)f2bf(v[i] - hf);
    }
}

// 1/(exp(2x)+1); tanh(x) = 1 - 2*sig2(x). exp saturation handles extremes.
__device__ __forceinline__ float sig2(float x) {
    float e = __expf(2.f * x);
    return __builtin_amdgcn_rcpf(e + 1.f);
}

// ---------------------------------------------------------------------------
// kW: Wv,Wg (49x512 f32) -> Whl[m][hl][64][512] bf16, rows >=49 zeroed.
__global__ __launch_bounds__(256) void kW(const float* __restrict__ Wv,
                                          const float* __restrict__ Wg,
                                          ushort* __restrict__ Whl)
{
    int blk = blockIdx.x;              // 0..127: m = blk>>6, row = blk&63
    int m = blk >> 6, row = blk & 63;
    const float* W = m ? Wg : Wv;
    int tid = threadIdx.x;
    ushort* hi = Whl + ((size_t)(m * 2 + 0) * 64 + row) * H_;
    ushort* lo = Whl + ((size_t)(m * 2 + 1) * 64 + row) * H_;
    #pragma unroll
    for (int c = tid; c < H_; c += 256) {
        float v = (row < A_) ? W[(size_t)row * H_ + c] : 0.f;
        ushort h = f2bf(v);
        float hf = __builtin_bit_cast(float, (uint)h << 16);
        hi[c] = h;
        lo[c] = f2bf(v - hf);
    }
}

// ---------------------------------------------------------------------------
// kAP: blocks [0,512): projection via split-bf16 MFMA. One 16-row tile per
//      block, one 16-a group per wave (pre-converted W, only X converted here).
//        tiles 0..255   (des):   C = W x des-rows -> cvT (B,64,K)
//        tiles 256..511 (title): C = title-rows x W -> cg (B*T,64)
//      blocks [512,2560): transpose des (B,K,H) f32 -> desT (B,H,K) bf16.
__global__ __launch_bounds__(256) void kAP(const float* __restrict__ des,
                                           const float* __restrict__ title,
                                           const ushort* __restrict__ Whl,
                                           float* __restrict__ cvT,
                                           float* __restrict__ cg,
                                           ushort* __restrict__ desT)
{
    __shared__ float Tls[32][33];
    int tid = threadIdx.x;

    if (blockIdx.x >= 512) {
        // ---- transpose branch ----
        int tb = blockIdx.x - 512;            // b(16) x kt(8) x ht(16)
        int b = tb >> 7, rem = tb & 127;
        int k0 = (rem >> 4) * 32, h0 = (rem & 15) * 32;
        int kk = tid >> 3, c4 = (tid & 7) * 4;
        float4 v = *(const float4*)(des + ((size_t)(b * K_ + k0 + kk) * H_) + h0 + c4);
        Tls[kk][c4 + 0] = v.x; Tls[kk][c4 + 1] = v.y;
        Tls[kk][c4 + 2] = v.z; Tls[kk][c4 + 3] = v.w;
        __syncthreads();
        int hh = tid >> 3;
        ushort4 o;
        o.x = f2bf(Tls[c4 + 0][hh]);
        o.y = f2bf(Tls[c4 + 1][hh]);
        o.z = f2bf(Tls[c4 + 2][hh]);
        o.w = f2bf(Tls[c4 + 3][hh]);
        *(ushort4*)(desT + ((size_t)(b * H_ + h0 + hh) * K_) + k0 + c4) = o;
        return;
    }

    // ---- projection branch ----
    int wv = tid >> 6, lane = tid & 63;
    int tile = blockIdx.x;                    // 0..511
    bool isDes = tile < 256;
    int lr = lane & 15, lc = lane >> 4;
    int g = wv;                               // a-group 0..3

    const float* X = isDes ? (des + (size_t)tile * 16 * H_)
                           : (title + (size_t)(tile - 256) * 16 * H_);
    int m = isDes ? 0 : 1;
    const ushort* whiP = Whl + ((size_t)(m * 2 + 0) * 64 + g * 16 + lr) * H_ + lc * 8;
    const ushort* wloP = Whl + ((size_t)(m * 2 + 1) * 64 + g * 16 + lr) * H_ + lc * 8;
    const float*  xp0  = X + (size_t)lr * H_ + lc * 8;

    f32x4 acc = {};

    for (int k0 = 0; k0 < H_; k0 += 32) {
        float4 xv0 = *(const float4*)(xp0 + k0);
        float4 xv1 = *(const float4*)(xp0 + k0 + 4);
        short8 xhi, xlo;
        cvt_hilo(xv0, xv1, xhi, xlo);
        short8 whi = *(const short8*)(whiP + k0);
        short8 wlo = *(const short8*)(wloP + k0);
        if (isDes) {     // A = W (rows=a), B = X (cols = k-row of des)
            acc = __builtin_amdgcn_mfma_f32_16x16x32_bf16(whi, xhi, acc, 0, 0, 0);
            acc = __builtin_amdgcn_mfma_f32_16x16x32_bf16(whi, xlo, acc, 0, 0, 0);
            acc = __builtin_amdgcn_mfma_f32_16x16x32_bf16(wlo, xhi, acc, 0, 0, 0);
        } else {         // A = X (rows=t), B = W (cols=a)
            acc = __builtin_amdgcn_mfma_f32_16x16x32_bf16(xhi, whi, acc, 0, 0, 0);
            acc = __builtin_amdgcn_mfma_f32_16x16x32_bf16(xlo, whi, acc, 0, 0, 0);
            acc = __builtin_amdgcn_mfma_f32_16x16x32_bf16(xhi, wlo, acc, 0, 0, 0);
        }
    }

    if (isDes) {
        int krows = tile * 16;
        int b = krows >> 8, kb = krows & 255;
        #pragma unroll
        for (int r = 0; r < 4; ++r) {
            int a = g * 16 + lc * 4 + r;           // C row = a
            cvT[((size_t)b * APAD + a) * K_ + kb + lr] = acc[r];
        }
    } else {
        int trows = (tile - 256) * 16;             // global title row (b*T+t)
        #pragma unroll
        for (int r = 0; r < 4; ++r) {
            int row = trows + lc * 4 + r;          // C row = t
            cg[(size_t)row * APAD + g * 16 + lr] = acc[r];
        }
    }
}

// ---------------------------------------------------------------------------
// kZ: fused z + softmax + PV. One block per (b, 8-row t-tile). 1024 threads.
// Thread (k = tid&255, tg = tid>>8) owns t = tg*2 + {0,1}.
// z = sumWh - 2 * sum_a Wh[a] * sig2(cv + cg). Softmax over k per t.
// PV: 16 waves x 32-h panels via bf16 MFMA (sA rows 8..15 zero-padded).
__global__ __launch_bounds__(1024, 8) void kZ(const float* __restrict__ cvT,
                                              const float* __restrict__ cg,
                                              const float* __restrict__ Wh,
                                              const ushort* __restrict__ desT,
                                              float* __restrict__ alpha,
                                              float* __restrict__ chat)
{
    __shared__ float  sCg[TT][APAD];
    __shared__ float  sWh[APAD];
    __shared__ float  sRedM[TT][4];
    __shared__ float  sRedS[TT][4];
    __shared__ ushort sA[16][K_ + 8];

    int bid = blockIdx.x;                 // 512: b = bid>>5, tile = bid&31
    int b  = bid >> 5;
    int t0 = (bid & 31) * TT;
    int tid = threadIdx.x;
    int k  = tid & 255;
    int tg = tid >> 8;                    // 0..3

    if (tid < TT * 16) {
        int row = tid >> 4, c = (tid & 15) * 4;
        *(float4*)(&sCg[row][c]) =
            *(const float4*)(cg + (size_t)(b * T_ + t0 + row) * APAD + c);
    } else if (tid < TT * 16 + APAD) {
        int a = tid - TT * 16;
        sWh[a] = (a < A_) ? Wh[a] : 0.f;
    }
    {   // zero sA rows 8..15 (PV reads 16 A-rows; only 8 are real)
        uint* zp = (uint*)&sA[TT][0];     // 8 rows x 264 ushort = 1056 uint
        if (tid < 1024) zp[tid] = 0;
        if (tid < 32)   zp[1024 + tid] = 0;
    }
    __syncthreads();

    // ---- z phase ----
    float zacc[2] = {0.f, 0.f};
    float sw = 0.f;
    const float* cvp = cvT + (size_t)b * APAD * K_ + k;
    int tb = tg * 2;

    for (int c = 0; c < 12; ++c) {
        int a0 = c * 4;
        float xa[4];
        #pragma unroll
        for (int i = 0; i < 4; ++i) xa[i] = cvp[(size_t)(a0 + i) * K_];
        float4 w4 = *(const float4*)(&sWh[a0]);
        float4 c0 = *(const float4*)(&sCg[tb][a0]);
        float4 c1 = *(const float4*)(&sCg[tb + 1][a0]);
        zacc[0] += w4.x * sig2(xa[0] + c0.x);
        zacc[1] += w4.x * sig2(xa[0] + c1.x);
        zacc[0] += w4.y * sig2(xa[1] + c0.y);
        zacc[1] += w4.y * sig2(xa[1] + c1.y);
        zacc[0] += w4.z * sig2(xa[2] + c0.z);
        zacc[1] += w4.z * sig2(xa[2] + c1.z);
        zacc[0] += w4.w * sig2(xa[3] + c0.w);
        zacc[1] += w4.w * sig2(xa[3] + c1.w);
        sw += w4.x + w4.y + w4.z + w4.w;
    }
    {   // tail a = 48
        float xa = cvp[(size_t)48 * K_];
        float wh = sWh[48];
        zacc[0] += wh * sig2(xa + sCg[tb][48]);
        zacc[1] += wh * sig2(xa + sCg[tb + 1][48]);
        sw += wh;
    }
    float z[2];
    z[0] = sw - 2.f * zacc[0];
    z[1] = sw - 2.f * zacc[1];

    // ---- softmax over k (4 waves per t) ----
    int wv = tid >> 6, lane = tid & 63, w3 = wv & 3;
    #pragma unroll
    for (int j = 0; j < 2; ++j) {
        float m = z[j];
        #pragma unroll
        for (int off = 32; off > 0; off >>= 1) m = fmaxf(m, __shfl_xor(m, off));
        if (lane == 0) sRedM[tb + j][w3] = m;
    }
    __syncthreads();
    #pragma unroll
    for (int j = 0; j < 2; ++j) {
        int t = tb + j;
        float m = fmaxf(fmaxf(sRedM[t][0], sRedM[t][1]),
                        fmaxf(sRedM[t][2], sRedM[t][3]));
        z[j] = __expf(z[j] - m);
    }
    #pragma unroll
    for (int j = 0; j < 2; ++j) {
        float s = z[j];
        #pragma unroll
        for (int off = 32; off > 0; off >>= 1) s += __shfl_xor(s, off);
        if (lane == 0) sRedS[tb + j][w3] = s;
    }
    __syncthreads();
    #pragma unroll
    for (int j = 0; j < 2; ++j) {
        int t = tb + j;
        float s = sRedS[t][0] + sRedS[t][1] + sRedS[t][2] + sRedS[t][3];
        float rs = __builtin_amdgcn_rcpf(s);
        rs = rs * (2.f - s * rs);              // Newton step
        float al = z[j] * rs;
        alpha[(size_t)(b * T_ + t0 + t) * K_ + k] = al;
        sA[t][k] = f2bf(al);
    }
    __syncthreads();

    // ---- PV: wave wv -> h-panel [wv*32, wv*32+32) ----
    int lr = lane & 15, lc = lane >> 4;
    int h0 = wv * 32;
    const ushort* Bp = desT + ((size_t)(b * H_ + h0 + lr)) * K_ + lc * 8;

    f32x4 acc0 = {}, acc1 = {};
    #pragma unroll
    for (int kb = 0; kb < K_; kb += 32) {
        short8 a8 = *(const short8*)(&sA[lr][kb + lc * 8]);
        short8 b0 = *(const short8*)(Bp + kb);
        short8 b1 = *(const short8*)(Bp + (size_t)16 * K_ + kb);
        acc0 = __builtin_amdgcn_mfma_f32_16x16x32_bf16(a8, b0, acc0, 0, 0, 0);
        acc1 = __builtin_amdgcn_mfma_f32_16x16x32_bf16(a8, b1, acc1, 0, 0, 0);
    }

    #pragma unroll
    for (int r = 0; r < 4; ++r) {
        int row = lc * 4 + r;
        if (row < TT) {
            chat[((size_t)(b * T_ + t0 + row)) * H_ + h0 + lr]      = acc0[r];
            chat[((size_t)(b * T_ + t0 + row)) * H_ + h0 + 16 + lr] = acc1[r];
        }
    }
}

// ---------------------------------------------------------------------------
extern "C" void kernel_launch(void* const* d_in, const int* in_sizes, int n_in,
                              void* d_out, int out_size, void* d_ws, size_t ws_size,
                              hipStream_t stream) {
    const float* des   = (const float*)d_in[0];
    const float* title = (const float*)d_in[1];
    const float* Wv    = (const float*)d_in[2];
    const float* Wg    = (const float*)d_in[3];
    const float* Wh    = (const float*)d_in[4];

    float* chat  = (float*)d_out;                            // (B,T,H)
    float* alpha = (float*)d_out + (size_t)B_ * T_ * H_;     // (B,T,K)

    char* ws = (char*)d_ws;
    float*  cvT  = (float*)ws;                               // (B,64,K) f32: 1 MB
    float*  cg   = cvT + (size_t)B_ * APAD * K_;             // (B*T,64) f32: 1 MB
    ushort* desT = (ushort*)(cg + (size_t)B_ * T_ * APAD);   // (B,H,K) bf16: 4 MB
    ushort* Whl  = desT + (size_t)B_ * H_ * K_;              // [2][2][64][512]: 256 KB

    hipLaunchKernelGGL(kW, dim3(128), dim3(256), 0, stream, Wv, Wg, Whl);
    hipLaunchKernelGGL(kAP, dim3(2560), dim3(256), 0, stream,
                       des, title, Whl, cvT, cg, desT);
    hipLaunchKernelGGL(kZ, dim3(B_ * (T_ / TT)), dim3(1024), 0, stream,
                       cvT, cg, Wh, desT, alpha, chat);
}

// Round 7
// 53.076 us; speedup vs baseline: 2.2236x; 2.2236x over previous
//
#include <hip/hip_runtime.h>
#include <hip/hip_bf16.h>

// Problem constants (Atten_tit): B=16, T=256, K=256, H=512, A=49
#define B_ 16
#define T_ 256
#define K_ 256
#define H_ 512
#define A_ 49
#define APAD 64

typedef __attribute__((ext_vector_type(8))) short short8;   // bf16x8
typedef __attribute__((ext_vector_type(4))) float f32x4;

__device__ __forceinline__ ushort f2bf(float f) {
    uint u = __builtin_bit_cast(uint, f);
    u += 0x7FFF + ((u >> 16) & 1);   // RNE
    return (ushort)(u >> 16);
}

// split f32 -> bf16 hi + bf16 lo (residual); hi+lo ~ 17 mantissa bits.
__device__ __forceinline__ void cvt_hilo(float4 v0, float4 v1, short8& hi, short8& lo) {
    float v[8] = {v0.x, v0.y, v0.z, v0.w, v1.x, v1.y, v1.z, v1.w};
    #pragma unroll
    for (int i = 0; i < 8; ++i) {
        ushort h = f2bf(v[i]);
        float hf = __builtin_bit_cast(float, (uint)h << 16);
        hi[i] = (short)h;
        lo[i] = (short)f2bf(v[i] - hf);
    }
}

// 1/(exp(2x)+1); tanh(x) = 1 - 2*sig2(x). exp saturation handles extremes.
__device__ __forceinline__ float sig2(float x) {
    float e = __expf(2.f * x);
    return __builtin_amdgcn_rcpf(e + 1.f);
}

// ---------------------------------------------------------------------------
// kW: Wv,Wg (49x512 f32) -> Whl[m][hl][64][512] bf16, rows >=49 zeroed.
__global__ __launch_bounds__(256) void kW(const float* __restrict__ Wv,
                                          const float* __restrict__ Wg,
                                          ushort* __restrict__ Whl)
{
    int blk = blockIdx.x;              // 0..127: m = blk>>6, row = blk&63
    int m = blk >> 6, row = blk & 63;
    const float* W = m ? Wg : Wv;
    int tid = threadIdx.x;
    ushort* hi = Whl + ((size_t)(m * 2 + 0) * 64 + row) * H_;
    ushort* lo = Whl + ((size_t)(m * 2 + 1) * 64 + row) * H_;
    #pragma unroll
    for (int c = tid; c < H_; c += 256) {
        float v = (row < A_) ? W[(size_t)row * H_ + c] : 0.f;
        ushort h = f2bf(v);
        float hf = __builtin_bit_cast(float, (uint)h << 16);
        hi[c] = h;
        lo[c] = f2bf(v - hf);
    }
}

// ---------------------------------------------------------------------------
// kAP: blocks [0,512): projection via split-bf16 MFMA. One 16-row tile per
//      block, one 16-a group per wave (pre-converted W, only X converted here).
//        tiles 0..255   (des):   C = W x des-rows -> cvT (B,64,K)
//        tiles 256..511 (title): C = title-rows x W -> cg (B*T,64)
//      blocks [512,2560): transpose des (B,K,H) f32 -> desT (B,H,K) bf16.
__global__ __launch_bounds__(256) void kAP(const float* __restrict__ des,
                                           const float* __restrict__ title,
                                           const ushort* __restrict__ Whl,
                                           float* __restrict__ cvT,
                                           float* __restrict__ cg,
                                           ushort* __restrict__ desT)
{
    __shared__ float Tls[32][33];
    int tid = threadIdx.x;

    if (blockIdx.x >= 512) {
        // ---- transpose branch ----
        int tb = blockIdx.x - 512;            // b(16) x kt(8) x ht(16)
        int b = tb >> 7, rem = tb & 127;
        int k0 = (rem >> 4) * 32, h0 = (rem & 15) * 32;
        int kk = tid >> 3, c4 = (tid & 7) * 4;
        float4 v = *(const float4*)(des + ((size_t)(b * K_ + k0 + kk) * H_) + h0 + c4);
        Tls[kk][c4 + 0] = v.x; Tls[kk][c4 + 1] = v.y;
        Tls[kk][c4 + 2] = v.z; Tls[kk][c4 + 3] = v.w;
        __syncthreads();
        int hh = tid >> 3;
        ushort4 o;
        o.x = f2bf(Tls[c4 + 0][hh]);
        o.y = f2bf(Tls[c4 + 1][hh]);
        o.z = f2bf(Tls[c4 + 2][hh]);
        o.w = f2bf(Tls[c4 + 3][hh]);
        *(ushort4*)(desT + ((size_t)(b * H_ + h0 + hh) * K_) + k0 + c4) = o;
        return;
    }

    // ---- projection branch ----
    int wv = tid >> 6, lane = tid & 63;
    int tile = blockIdx.x;                    // 0..511
    bool isDes = tile < 256;
    int lr = lane & 15, lc = lane >> 4;
    int g = wv;                               // a-group 0..3

    const float* X = isDes ? (des + (size_t)tile * 16 * H_)
                           : (title + (size_t)(tile - 256) * 16 * H_);
    int m = isDes ? 0 : 1;
    const ushort* whiP = Whl + ((size_t)(m * 2 + 0) * 64 + g * 16 + lr) * H_ + lc * 8;
    const ushort* wloP = Whl + ((size_t)(m * 2 + 1) * 64 + g * 16 + lr) * H_ + lc * 8;
    const float*  xp0  = X + (size_t)lr * H_ + lc * 8;

    f32x4 acc = {};

    for (int k0 = 0; k0 < H_; k0 += 32) {
        float4 xv0 = *(const float4*)(xp0 + k0);
        float4 xv1 = *(const float4*)(xp0 + k0 + 4);
        short8 xhi, xlo;
        cvt_hilo(xv0, xv1, xhi, xlo);
        short8 whi = *(const short8*)(whiP + k0);
        short8 wlo = *(const short8*)(wloP + k0);
        if (isDes) {     // A = W (rows=a), B = X (cols = k-row of des)
            acc = __builtin_amdgcn_mfma_f32_16x16x32_bf16(whi, xhi, acc, 0, 0, 0);
            acc = __builtin_amdgcn_mfma_f32_16x16x32_bf16(whi, xlo, acc, 0, 0, 0);
            acc = __builtin_amdgcn_mfma_f32_16x16x32_bf16(wlo, xhi, acc, 0, 0, 0);
        } else {         // A = X (rows=t), B = W (cols=a)
            acc = __builtin_amdgcn_mfma_f32_16x16x32_bf16(xhi, whi, acc, 0, 0, 0);
            acc = __builtin_amdgcn_mfma_f32_16x16x32_bf16(xlo, whi, acc, 0, 0, 0);
            acc = __builtin_amdgcn_mfma_f32_16x16x32_bf16(xhi, wlo, acc, 0, 0, 0);
        }
    }

    if (isDes) {
        int krows = tile * 16;
        int b = krows >> 8, kb = krows & 255;
        #pragma unroll
        for (int r = 0; r < 4; ++r) {
            int a = g * 16 + lc * 4 + r;           // C row = a
            cvT[((size_t)b * APAD + a) * K_ + kb + lr] = acc[r];
        }
    } else {
        int trows = (tile - 256) * 16;             // global title row (b*T+t)
        #pragma unroll
        for (int r = 0; r < 4; ++r) {
            int row = trows + lc * 4 + r;          // C row = t
            cg[(size_t)row * APAD + g * 16 + lr] = acc[r];
        }
    }
}

// ---------------------------------------------------------------------------
// kZ: fused z + softmax + PV. One block per (b, 16-row t-tile). 1024 threads.
// b = blockIdx.x & 15 so consecutive blocks (round-robin across XCDs) pin each
// b's desT slice (256 KB) to ~1 XCD L2 (T1: 2 slices/XCD = 512 KB << 4 MB).
// Thread (k = tid&255, tg = tid>>8) owns t = tg*4 + {0..3}.
// z = sumWh - 2*sum_a Wh[a]*sig2(cv+cg); softmax over k; PV: 16 waves x 32-h.
__global__ __launch_bounds__(1024) void kZ(const float* __restrict__ cvT,
                                           const float* __restrict__ cg,
                                           const float* __restrict__ Wh,
                                           const ushort* __restrict__ desT,
                                           float* __restrict__ alpha,
                                           float* __restrict__ chat)
{
    __shared__ float  sCg[16][APAD];
    __shared__ float  sWh[APAD];
    __shared__ float  sRedM[16][4];
    __shared__ float  sRedS[16][4];
    __shared__ ushort sA[16][K_ + 8];

    int bid = blockIdx.x;                 // 256 blocks
    int b  = bid & 15;                    // XCD-local b (T1 swizzle)
    int t0 = (bid >> 4) << 4;
    int tid = threadIdx.x;
    int k  = tid & 255;
    int tg = tid >> 8;                    // 0..3
    int tb = tg * 4;

    if (tid < 256) {
        int row = tid >> 4, c = (tid & 15) * 4;
        *(float4*)(&sCg[row][c]) =
            *(const float4*)(cg + (size_t)(b * T_ + t0 + row) * APAD + c);
    } else if (tid < 256 + APAD) {
        int a = tid - 256;
        sWh[a] = (a < A_) ? Wh[a] : 0.f;
    }
    __syncthreads();

    // ---- z phase: 4 t's per thread, a blocked by 4 ----
    float zacc[4] = {0.f, 0.f, 0.f, 0.f};
    float sw = 0.f;
    const float* cvp = cvT + (size_t)b * APAD * K_ + k;

    for (int c = 0; c < 12; ++c) {
        int a0 = c * 4;
        float xa[4];
        #pragma unroll
        for (int i = 0; i < 4; ++i) xa[i] = cvp[(size_t)(a0 + i) * K_];
        float4 w4 = *(const float4*)(&sWh[a0]);
        sw += w4.x + w4.y + w4.z + w4.w;
        #pragma unroll
        for (int j = 0; j < 4; ++j) {
            float4 cj = *(const float4*)(&sCg[tb + j][a0]);
            zacc[j] += w4.x * sig2(xa[0] + cj.x)
                     + w4.y * sig2(xa[1] + cj.y)
                     + w4.z * sig2(xa[2] + cj.z)
                     + w4.w * sig2(xa[3] + cj.w);
        }
    }
    {   // tail a = 48
        float xa = cvp[(size_t)48 * K_];
        float wh = sWh[48];
        sw += wh;
        #pragma unroll
        for (int j = 0; j < 4; ++j)
            zacc[j] += wh * sig2(xa + sCg[tb + j][48]);
    }
    float z[4];
    #pragma unroll
    for (int j = 0; j < 4; ++j) z[j] = sw - 2.f * zacc[j];

    // ---- softmax over k (4 waves per tg group) ----
    int wv = tid >> 6, lane = tid & 63, w3 = wv & 3;
    #pragma unroll
    for (int j = 0; j < 4; ++j) {
        float m = z[j];
        #pragma unroll
        for (int off = 32; off > 0; off >>= 1) m = fmaxf(m, __shfl_xor(m, off));
        if (lane == 0) sRedM[tb + j][w3] = m;
    }
    __syncthreads();
    #pragma unroll
    for (int j = 0; j < 4; ++j) {
        int t = tb + j;
        float m = fmaxf(fmaxf(sRedM[t][0], sRedM[t][1]),
                        fmaxf(sRedM[t][2], sRedM[t][3]));
        z[j] = __expf(z[j] - m);
    }
    #pragma unroll
    for (int j = 0; j < 4; ++j) {
        float s = z[j];
        #pragma unroll
        for (int off = 32; off > 0; off >>= 1) s += __shfl_xor(s, off);
        if (lane == 0) sRedS[tb + j][w3] = s;
    }
    __syncthreads();
    #pragma unroll
    for (int j = 0; j < 4; ++j) {
        int t = tb + j;
        float s = sRedS[t][0] + sRedS[t][1] + sRedS[t][2] + sRedS[t][3];
        float rs = __builtin_amdgcn_rcpf(s);
        rs = rs * (2.f - s * rs);              // Newton step
        float al = z[j] * rs;
        alpha[(size_t)(b * T_ + t0 + t) * K_ + k] = al;
        sA[t][k] = f2bf(al);
    }
    __syncthreads();

    // ---- PV: wave wv -> h-panel [wv*32, wv*32+32) ----
    int lr = lane & 15, lc = lane >> 4;
    int h0 = wv * 32;
    const ushort* Bp = desT + ((size_t)(b * H_ + h0 + lr)) * K_ + lc * 8;

    f32x4 acc0 = {}, acc1 = {};
    #pragma unroll
    for (int kb = 0; kb < K_; kb += 32) {
        short8 a8 = *(const short8*)(&sA[lr][kb + lc * 8]);
        short8 b0 = *(const short8*)(Bp + kb);
        short8 b1 = *(const short8*)(Bp + (size_t)16 * K_ + kb);
        acc0 = __builtin_amdgcn_mfma_f32_16x16x32_bf16(a8, b0, acc0, 0, 0, 0);
        acc1 = __builtin_amdgcn_mfma_f32_16x16x32_bf16(a8, b1, acc1, 0, 0, 0);
    }

    #pragma unroll
    for (int r = 0; r < 4; ++r) {
        int row = t0 + lc * 4 + r;
        chat[((size_t)(b * T_ + row)) * H_ + h0 + lr]      = acc0[r];
        chat[((size_t)(b * T_ + row)) * H_ + h0 + 16 + lr] = acc1[r];
    }
}

// ---------------------------------------------------------------------------
extern "C" void kernel_launch(void* const* d_in, const int* in_sizes, int n_in,
                              void* d_out, int out_size, void* d_ws, size_t ws_size,
                              hipStream_t stream) {
    const float* des   = (const float*)d_in[0];
    const float* title = (const float*)d_in[1];
    const float* Wv    = (const float*)d_in[2];
    const float* Wg    = (const float*)d_in[3];
    const float* Wh    = (const float*)d_in[4];

    float* chat  = (float*)d_out;                            // (B,T,H)
    float* alpha = (float*)d_out + (size_t)B_ * T_ * H_;     // (B,T,K)

    char* ws = (char*)d_ws;
    float*  cvT  = (float*)ws;                               // (B,64,K) f32: 1 MB
    float*  cg   = cvT + (size_t)B_ * APAD * K_;             // (B*T,64) f32: 1 MB
    ushort* desT = (ushort*)(cg + (size_t)B_ * T_ * APAD);   // (B,H,K) bf16: 4 MB
    ushort* Whl  = desT + (size_t)B_ * H_ * K_;              // [2][2][64][512]: 256 KB

    hipLaunchKernelGGL(kW, dim3(128), dim3(256), 0, stream, Wv, Wg, Whl);
    hipLaunchKernelGGL(kAP, dim3(2560), dim3(256), 0, stream,
                       des, title, Whl, cvT, cg, desT);
    hipLaunchKernelGGL(kZ, dim3(B_ * (T_ / 16)), dim3(1024), 0, stream,
                       cvT, cg, Wh, desT, alpha, chat);
}